// Round 2
// baseline (1984.552 us; speedup 1.0000x reference)
//
#include <hip/hip_runtime.h>
#include <hip/hip_bf16.h>
#include <math.h>

#define N_TOK 16384
#define D_DIM 2048
#define E_EXP 64
#define NTILES 256   /* N_TOK / 64 */

// ---------------------------------------------------------------------------
// GEMM: part[s][t][e] = sum_{k in split s} x[t][k] * W[e][k]
// grid = NTILES * nsplit, 256 threads. Tile: 64 tok x 64 exp, thread 4x4
// (experts 4*tx..4*tx+3 -> float4 stores). Both x and W staged in LDS,
// double-buffered, XOR-swizzled slots, one barrier per 32-wide K chunk.
// ---------------------------------------------------------------------------
__global__ __launch_bounds__(256, 4)
void router_gemm(const float* __restrict__ x, const float* __restrict__ W,
                 float* __restrict__ part, int kper) {
  __shared__ float s_x[2][64 * 32];
  __shared__ float s_w[2][64 * 32];
  const int tile  = blockIdx.x & (NTILES - 1);
  const int split = blockIdx.x >> 8;           // NTILES == 256
  const int tid = threadIdx.x;
  const int tx = tid & 15;        // expert group: experts 4*tx + j
  const int ty = tid >> 4;        // token group:  tokens 16*i + ty
  const int k0base = split * kper;
  const int nchunk = kper >> 5;   // K chunks of 32

  float acc[4][4];
#pragma unroll
  for (int i = 0; i < 4; ++i)
#pragma unroll
    for (int j = 0; j < 4; ++j) acc[i][j] = 0.f;

  // staging: 512 float4 per buffer per matrix; 2 per thread each
  const int r0 = tid >> 3;        // 0..31
  const int c0 = tid & 7;         // float4 slot 0..7

  const float* xg0 = x + (size_t)(tile * 64 + r0) * D_DIM + k0base + c0 * 4;
  const float* xg1 = xg0 + (size_t)32 * D_DIM;
  const float* wg0 = W + (size_t)r0 * D_DIM + k0base + c0 * 4;
  const float* wg1 = wg0 + (size_t)32 * D_DIM;

  // x swizzle: slot' = c0 ^ (row&7); rows r0 and r0+32 share (row&7)
  const int sx0 = r0 * 32 + ((c0 ^ (r0 & 7)) * 4);
  const int sx1 = sx0 + 32 * 32;
  // w swizzle: slot' = c0 ^ ((row>>2)&7); rows r0 and r0+32 share ((row>>2)&7)
  const int sw0 = r0 * 32 + ((c0 ^ ((r0 >> 2) & 7)) * 4);
  const int sw1 = sw0 + 32 * 32;

  float4 a0, a1, b0, b1;
  a0 = *(const float4*)(xg0);
  a1 = *(const float4*)(xg1);
  b0 = *(const float4*)(wg0);
  b1 = *(const float4*)(wg1);
  *(float4*)(&s_x[0][sx0]) = a0;
  *(float4*)(&s_x[0][sx1]) = a1;
  *(float4*)(&s_w[0][sw0]) = b0;
  *(float4*)(&s_w[0][sw1]) = b1;
  __syncthreads();

  for (int c = 0; c < nchunk; ++c) {
    const int cur = c & 1;
    if (c + 1 < nchunk) {   // issue next-chunk loads early (latency hides under FMA)
      const int off = (c + 1) * 32;
      a0 = *(const float4*)(xg0 + off);
      a1 = *(const float4*)(xg1 + off);
      b0 = *(const float4*)(wg0 + off);
      b1 = *(const float4*)(wg1 + off);
    }
    const float* px = s_x[cur];
    const float* pw = s_w[cur];
#pragma unroll
    for (int s = 0; s < 8; ++s) {
      const int xs = (s ^ (ty & 7)) * 4;   // row&7 == ty&7 for rows 16i+ty
      const int ws = (s ^ (tx & 7)) * 4;   // (e>>2)&7 == tx&7 for e=4tx+j
      float4 xv[4], wv[4];
#pragma unroll
      for (int i = 0; i < 4; ++i)
        xv[i] = *(const float4*)(px + (16 * i + ty) * 32 + xs);
#pragma unroll
      for (int j = 0; j < 4; ++j)
        wv[j] = *(const float4*)(pw + (4 * tx + j) * 32 + ws);
#pragma unroll
      for (int i = 0; i < 4; ++i)
#pragma unroll
        for (int j = 0; j < 4; ++j)
          acc[i][j] += xv[i].x * wv[j].x + xv[i].y * wv[j].y +
                       xv[i].z * wv[j].z + xv[i].w * wv[j].w;
    }
    if (c + 1 < nchunk) {   // write-late into the other buffer (safe: its
      const int nxt = cur ^ 1;             // readers passed the last barrier)
      *(float4*)(&s_x[nxt][sx0]) = a0;
      *(float4*)(&s_x[nxt][sx1]) = a1;
      *(float4*)(&s_w[nxt][sw0]) = b0;
      *(float4*)(&s_w[nxt][sw1]) = b1;
    }
    __syncthreads();
  }

#pragma unroll
  for (int i = 0; i < 4; ++i) {
    const int t = tile * 64 + 16 * i + ty;
    float4 v = make_float4(acc[i][0], acc[i][1], acc[i][2], acc[i][3]);
    *(float4*)(part + ((size_t)split * N_TOK + t) * 64 + 4 * tx) = v;
  }
}

// ---------------------------------------------------------------------------
// Epilogue: one token per thread. Sum split partials -> 64 logits in regs.
// top-2 (lax.top_k tie-break = lowest index first), gates, lse, probs.
// ---------------------------------------------------------------------------
__global__ __launch_bounds__(256)
void epilogue(const float* __restrict__ part, int nsplit,
              float* __restrict__ out,             // d_out base (float)
              double* __restrict__ p_sum_d,
              unsigned* __restrict__ freq,
              double* __restrict__ lsesq_d) {
  const int tid  = threadIdx.x;
  const int t    = blockIdx.x * 256 + tid;
  const int lane = tid & 63;
  const int wv   = tid >> 6;

  float l[64];
  {
    const float* p0 = part + (size_t)t * 64;
#pragma unroll
    for (int q = 0; q < 16; ++q) {
      float4 a = *(const float4*)(p0 + q * 4);
      l[q * 4 + 0] = a.x; l[q * 4 + 1] = a.y;
      l[q * 4 + 2] = a.z; l[q * 4 + 3] = a.w;
    }
  }
  for (int s = 1; s < nsplit; ++s) {
    const float* ps = part + ((size_t)s * N_TOK + t) * 64;
#pragma unroll
    for (int q = 0; q < 16; ++q) {
      float4 a = *(const float4*)(ps + q * 4);
      l[q * 4 + 0] += a.x; l[q * 4 + 1] += a.y;
      l[q * 4 + 2] += a.z; l[q * 4 + 3] += a.w;
    }
  }

  // row max
  float m = l[0];
#pragma unroll
  for (int e = 1; e < 64; ++e) m = fmaxf(m, l[e]);

  // exp sum
  float sum = 0.f;
#pragma unroll
  for (int e = 0; e < 64; ++e) sum += __expf(l[e] - m);
  const float lse = m + __logf(sum);
  const float inv = 1.0f / sum;

  // top-2 scan, strict > keeps lowest index on ties (lax.top_k semantics)
  float v0 = l[0], v1 = -3.402823466e38f;
  int i0 = 0, i1 = 0;
#pragma unroll
  for (int e = 1; e < 64; ++e) {
    float le = l[e];
    bool g0 = le > v0;
    bool g1 = le > v1;
    float nv1 = g0 ? v0 : (g1 ? le : v1);
    int   ni1 = g0 ? i0 : (g1 ? e  : i1);
    float nv0 = g0 ? le : v0;
    int   ni0 = g0 ? e  : i0;
    v0 = nv0; i0 = ni0; v1 = nv1; i1 = ni1;
  }

  // gates = softmax([v0, v1])
  float d  = __expf(v1 - v0);
  float g0 = 1.0f / (1.0f + d);
  float g1 = d * g0;

  out[t * 2 + 0] = (float)i0;
  out[t * 2 + 1] = (float)i1;
  out[2 * N_TOK + t * 2 + 0] = g0;
  out[2 * N_TOK + t * 2 + 1] = g1;

  // ---- freq histogram (exact ints) ----
  __shared__ unsigned hist[64];
  if (tid < 64) hist[tid] = 0u;
  __syncthreads();
  atomicAdd(&hist[i0], 1u);
  atomicAdd(&hist[i1], 1u);

  // ---- p_sum: wave butterfly per expert ----
  float myps = 0.f;
#pragma unroll
  for (int e = 0; e < 64; ++e) {
    float v = __expf(l[e] - m) * inv;
    v += __shfl_xor(v, 32, 64);
    v += __shfl_xor(v, 16, 64);
    v += __shfl_xor(v, 8, 64);
    v += __shfl_xor(v, 4, 64);
    v += __shfl_xor(v, 2, 64);
    v += __shfl_xor(v, 1, 64);
    myps = (lane == e) ? v : myps;
  }

  __shared__ float s_ps[4][64];
  s_ps[wv][lane] = myps;

  // ---- lse^2 wave reduce ----
  float z = lse * lse;
  z += __shfl_xor(z, 32, 64);
  z += __shfl_xor(z, 16, 64);
  z += __shfl_xor(z, 8, 64);
  z += __shfl_xor(z, 4, 64);
  z += __shfl_xor(z, 2, 64);
  z += __shfl_xor(z, 1, 64);
  __shared__ double s_z[4];
  if (lane == 0) s_z[wv] = (double)z;

  __syncthreads();
  if (tid < 64) {
    float tot = s_ps[0][tid] + s_ps[1][tid] + s_ps[2][tid] + s_ps[3][tid];
    atomicAdd(&p_sum_d[tid], (double)tot);
    atomicAdd(&freq[tid], hist[tid]);
  }
  if (tid == 0) {
    atomicAdd(lsesq_d, s_z[0] + s_z[1] + s_z[2] + s_z[3]);
  }
}

// ---------------------------------------------------------------------------
// Finalize: switchloss + 0.1 * z_loss  (1 block, 64 threads)
// ---------------------------------------------------------------------------
__global__ void finalize(const double* __restrict__ p_sum_d,
                         const unsigned* __restrict__ freq,
                         const double* __restrict__ lsesq_d,
                         float* __restrict__ out_loss) {
  const int lane = threadIdx.x;
  double p = p_sum_d[lane];
  double f = (double)freq[lane];

  double pa = fabs(p);
  double fa = fabs(f);
#pragma unroll
  for (int off = 32; off >= 1; off >>= 1) {
    pa += __shfl_xor(pa, off, 64);
    fa += __shfl_xor(fa, off, 64);
  }
  pa = pa > 1e-12 ? pa : 1e-12;
  fa = fa > 1e-12 ? fa : 1e-12;

  double s = (p / pa) * (f / fa);
#pragma unroll
  for (int off = 32; off >= 1; off >>= 1) s += __shfl_xor(s, off, 64);

  if (lane == 0) {
    double switchloss = 64.0 * s;
    double z_loss = lsesq_d[0] / (double)N_TOK;
    out_loss[0] = (float)(switchloss + 0.1 * z_loss);
  }
}

extern "C" void kernel_launch(void* const* d_in, const int* in_sizes, int n_in,
                              void* d_out, int out_size, void* d_ws, size_t ws_size,
                              hipStream_t stream) {
  const float* x = (const float*)d_in[0];
  const float* W = (const float*)d_in[1];
  float* out = (float*)d_out;

  const size_t partB = (size_t)N_TOK * 64 * 4;  // 4 MB per split
  int S = 4;
  while (S > 1 && (size_t)S * partB + 4096 > ws_size) S >>= 1;

  float* part = (float*)d_ws;
  size_t tail = ((size_t)S * partB + 511) & ~(size_t)511;
  double* p_sum_d = (double*)((char*)d_ws + tail);
  double* lsesq_d = p_sum_d + 64;
  unsigned* freq  = (unsigned*)(lsesq_d + 1);

  hipMemsetAsync((char*)d_ws + tail, 0, 64 * 8 + 8 + 64 * 4, stream);

  router_gemm<<<NTILES * S, 256, 0, stream>>>(x, W, part, D_DIM / S);
  epilogue<<<N_TOK / 256, 256, 0, stream>>>(part, S, out, p_sum_d, freq, lsesq_d);
  finalize<<<1, 64, 0, stream>>>(p_sum_d, freq, lsesq_d, out + 4 * N_TOK);
}

// Round 3
// 149.226 us; speedup vs baseline: 13.2990x; 13.2990x over previous
//
#include <hip/hip_runtime.h>
#include <hip/hip_bf16.h>
#include <math.h>

#define N_TOK 16384
#define D_DIM 2048
#define E_EXP 64
#define NTILES 256   /* N_TOK / 64 */

// ---------------------------------------------------------------------------
// GEMM: part[s][t][e] = sum_{k in split s} x[t][k] * W[e][k]
// grid = NTILES * nsplit, 256 threads. Tile: 64 tok x 64 exp, thread 4x4
// (experts 4*tx..4*tx+3 -> float4 stores). Both x and W staged in LDS,
// double-buffered, XOR-swizzled slots, one barrier per 32-wide K chunk.
// NOTE: no min-occupancy launch_bounds — R2's (256,4) pinned VGPR=64 and
// spilled ~17KB/thread to scratch (4.5 GB HBM writes). Let regalloc breathe.
// ---------------------------------------------------------------------------
__global__ __launch_bounds__(256)
void router_gemm(const float* __restrict__ x, const float* __restrict__ W,
                 float* __restrict__ part, int kper) {
  __shared__ float s_x[2][64 * 32];
  __shared__ float s_w[2][64 * 32];
  const int tile  = blockIdx.x & (NTILES - 1);
  const int split = blockIdx.x >> 8;           // NTILES == 256
  const int tid = threadIdx.x;
  const int tx = tid & 15;        // expert group: experts 4*tx + j
  const int ty = tid >> 4;        // token group:  tokens 16*i + ty
  const int k0base = split * kper;
  const int nchunk = kper >> 5;   // K chunks of 32

  float acc[4][4];
#pragma unroll
  for (int i = 0; i < 4; ++i)
#pragma unroll
    for (int j = 0; j < 4; ++j) acc[i][j] = 0.f;

  // staging: 512 float4 per buffer per matrix; 2 per thread each
  const int r0 = tid >> 3;        // 0..31
  const int c0 = tid & 7;         // float4 slot 0..7

  const float* xg0 = x + (size_t)(tile * 64 + r0) * D_DIM + k0base + c0 * 4;
  const float* xg1 = xg0 + (size_t)32 * D_DIM;
  const float* wg0 = W + (size_t)r0 * D_DIM + k0base + c0 * 4;
  const float* wg1 = wg0 + (size_t)32 * D_DIM;

  // x swizzle: slot' = c0 ^ (row&7); rows r0 and r0+32 share (row&7)
  const int sx0 = r0 * 32 + ((c0 ^ (r0 & 7)) * 4);
  const int sx1 = sx0 + 32 * 32;
  // w swizzle: slot' = c0 ^ ((row>>2)&7); rows r0 and r0+32 share ((row>>2)&7)
  const int sw0 = r0 * 32 + ((c0 ^ ((r0 >> 2) & 7)) * 4);
  const int sw1 = sw0 + 32 * 32;

  float4 a0, a1, b0, b1;
  a0 = *(const float4*)(xg0);
  a1 = *(const float4*)(xg1);
  b0 = *(const float4*)(wg0);
  b1 = *(const float4*)(wg1);
  *(float4*)(&s_x[0][sx0]) = a0;
  *(float4*)(&s_x[0][sx1]) = a1;
  *(float4*)(&s_w[0][sw0]) = b0;
  *(float4*)(&s_w[0][sw1]) = b1;
  __syncthreads();

  for (int c = 0; c < nchunk; ++c) {
    const int cur = c & 1;
    if (c + 1 < nchunk) {   // issue next-chunk loads early (latency hides under FMA)
      const int off = (c + 1) * 32;
      a0 = *(const float4*)(xg0 + off);
      a1 = *(const float4*)(xg1 + off);
      b0 = *(const float4*)(wg0 + off);
      b1 = *(const float4*)(wg1 + off);
    }
    const float* px = s_x[cur];
    const float* pw = s_w[cur];
#pragma unroll
    for (int s = 0; s < 8; ++s) {
      const int xs = (s ^ (ty & 7)) * 4;   // row&7 == ty&7 for rows 16i+ty
      const int ws = (s ^ (tx & 7)) * 4;   // (e>>2)&7 == tx&7 for e=4tx+j
      float4 xv[4], wv[4];
#pragma unroll
      for (int i = 0; i < 4; ++i)
        xv[i] = *(const float4*)(px + (16 * i + ty) * 32 + xs);
#pragma unroll
      for (int j = 0; j < 4; ++j)
        wv[j] = *(const float4*)(pw + (4 * tx + j) * 32 + ws);
#pragma unroll
      for (int i = 0; i < 4; ++i)
#pragma unroll
        for (int j = 0; j < 4; ++j)
          acc[i][j] += xv[i].x * wv[j].x + xv[i].y * wv[j].y +
                       xv[i].z * wv[j].z + xv[i].w * wv[j].w;
    }
    if (c + 1 < nchunk) {   // write-late into the other buffer (safe: its
      const int nxt = cur ^ 1;             // readers passed the last barrier)
      *(float4*)(&s_x[nxt][sx0]) = a0;
      *(float4*)(&s_x[nxt][sx1]) = a1;
      *(float4*)(&s_w[nxt][sw0]) = b0;
      *(float4*)(&s_w[nxt][sw1]) = b1;
    }
    __syncthreads();
  }

#pragma unroll
  for (int i = 0; i < 4; ++i) {
    const int t = tile * 64 + 16 * i + ty;
    float4 v = make_float4(acc[i][0], acc[i][1], acc[i][2], acc[i][3]);
    *(float4*)(part + ((size_t)split * N_TOK + t) * 64 + 4 * tx) = v;
  }
}

// ---------------------------------------------------------------------------
// Epilogue: one token per thread. Sum split partials -> 64 logits in regs.
// top-2 (lax.top_k tie-break = lowest index first), gates, lse, probs.
// ---------------------------------------------------------------------------
__global__ __launch_bounds__(256)
void epilogue(const float* __restrict__ part, int nsplit,
              float* __restrict__ out,             // d_out base (float)
              double* __restrict__ p_sum_d,
              unsigned* __restrict__ freq,
              double* __restrict__ lsesq_d) {
  const int tid  = threadIdx.x;
  const int t    = blockIdx.x * 256 + tid;
  const int lane = tid & 63;
  const int wv   = tid >> 6;

  float l[64];
  {
    const float* p0 = part + (size_t)t * 64;
#pragma unroll
    for (int q = 0; q < 16; ++q) {
      float4 a = *(const float4*)(p0 + q * 4);
      l[q * 4 + 0] = a.x; l[q * 4 + 1] = a.y;
      l[q * 4 + 2] = a.z; l[q * 4 + 3] = a.w;
    }
  }
  for (int s = 1; s < nsplit; ++s) {
    const float* ps = part + ((size_t)s * N_TOK + t) * 64;
#pragma unroll
    for (int q = 0; q < 16; ++q) {
      float4 a = *(const float4*)(ps + q * 4);
      l[q * 4 + 0] += a.x; l[q * 4 + 1] += a.y;
      l[q * 4 + 2] += a.z; l[q * 4 + 3] += a.w;
    }
  }

  // row max
  float m = l[0];
#pragma unroll
  for (int e = 1; e < 64; ++e) m = fmaxf(m, l[e]);

  // exp sum
  float sum = 0.f;
#pragma unroll
  for (int e = 0; e < 64; ++e) sum += __expf(l[e] - m);
  const float lse = m + __logf(sum);
  const float inv = 1.0f / sum;

  // top-2 scan, strict > keeps lowest index on ties (lax.top_k semantics)
  float v0 = l[0], v1 = -3.402823466e38f;
  int i0 = 0, i1 = 0;
#pragma unroll
  for (int e = 1; e < 64; ++e) {
    float le = l[e];
    bool g0 = le > v0;
    bool g1 = le > v1;
    float nv1 = g0 ? v0 : (g1 ? le : v1);
    int   ni1 = g0 ? i0 : (g1 ? e  : i1);
    float nv0 = g0 ? le : v0;
    int   ni0 = g0 ? e  : i0;
    v0 = nv0; i0 = ni0; v1 = nv1; i1 = ni1;
  }

  // gates = softmax([v0, v1])
  float d  = __expf(v1 - v0);
  float g0 = 1.0f / (1.0f + d);
  float g1 = d * g0;

  out[t * 2 + 0] = (float)i0;
  out[t * 2 + 1] = (float)i1;
  out[2 * N_TOK + t * 2 + 0] = g0;
  out[2 * N_TOK + t * 2 + 1] = g1;

  // ---- freq histogram (exact ints) ----
  __shared__ unsigned hist[64];
  if (tid < 64) hist[tid] = 0u;
  __syncthreads();
  atomicAdd(&hist[i0], 1u);
  atomicAdd(&hist[i1], 1u);

  // ---- p_sum: wave butterfly per expert ----
  float myps = 0.f;
#pragma unroll
  for (int e = 0; e < 64; ++e) {
    float v = __expf(l[e] - m) * inv;
    v += __shfl_xor(v, 32, 64);
    v += __shfl_xor(v, 16, 64);
    v += __shfl_xor(v, 8, 64);
    v += __shfl_xor(v, 4, 64);
    v += __shfl_xor(v, 2, 64);
    v += __shfl_xor(v, 1, 64);
    myps = (lane == e) ? v : myps;
  }

  __shared__ float s_ps[4][64];
  s_ps[wv][lane] = myps;

  // ---- lse^2 wave reduce ----
  float z = lse * lse;
  z += __shfl_xor(z, 32, 64);
  z += __shfl_xor(z, 16, 64);
  z += __shfl_xor(z, 8, 64);
  z += __shfl_xor(z, 4, 64);
  z += __shfl_xor(z, 2, 64);
  z += __shfl_xor(z, 1, 64);
  __shared__ double s_z[4];
  if (lane == 0) s_z[wv] = (double)z;

  __syncthreads();
  if (tid < 64) {
    float tot = s_ps[0][tid] + s_ps[1][tid] + s_ps[2][tid] + s_ps[3][tid];
    atomicAdd(&p_sum_d[tid], (double)tot);
    atomicAdd(&freq[tid], hist[tid]);
  }
  if (tid == 0) {
    atomicAdd(lsesq_d, s_z[0] + s_z[1] + s_z[2] + s_z[3]);
  }
}

// ---------------------------------------------------------------------------
// Finalize: switchloss + 0.1 * z_loss  (1 block, 64 threads)
// ---------------------------------------------------------------------------
__global__ void finalize(const double* __restrict__ p_sum_d,
                         const unsigned* __restrict__ freq,
                         const double* __restrict__ lsesq_d,
                         float* __restrict__ out_loss) {
  const int lane = threadIdx.x;
  double p = p_sum_d[lane];
  double f = (double)freq[lane];

  double pa = fabs(p);
  double fa = fabs(f);
#pragma unroll
  for (int off = 32; off >= 1; off >>= 1) {
    pa += __shfl_xor(pa, off, 64);
    fa += __shfl_xor(fa, off, 64);
  }
  pa = pa > 1e-12 ? pa : 1e-12;
  fa = fa > 1e-12 ? fa : 1e-12;

  double s = (p / pa) * (f / fa);
#pragma unroll
  for (int off = 32; off >= 1; off >>= 1) s += __shfl_xor(s, off, 64);

  if (lane == 0) {
    double switchloss = 64.0 * s;
    double z_loss = lsesq_d[0] / (double)N_TOK;
    out_loss[0] = (float)(switchloss + 0.1 * z_loss);
  }
}

extern "C" void kernel_launch(void* const* d_in, const int* in_sizes, int n_in,
                              void* d_out, int out_size, void* d_ws, size_t ws_size,
                              hipStream_t stream) {
  const float* x = (const float*)d_in[0];
  const float* W = (const float*)d_in[1];
  float* out = (float*)d_out;

  const size_t partB = (size_t)N_TOK * 64 * 4;  // 4 MB per split
  int S = 4;
  while (S > 1 && (size_t)S * partB + 4096 > ws_size) S >>= 1;

  float* part = (float*)d_ws;
  size_t tail = ((size_t)S * partB + 511) & ~(size_t)511;
  double* p_sum_d = (double*)((char*)d_ws + tail);
  double* lsesq_d = p_sum_d + 64;
  unsigned* freq  = (unsigned*)(lsesq_d + 1);

  hipMemsetAsync((char*)d_ws + tail, 0, 64 * 8 + 8 + 64 * 4, stream);

  router_gemm<<<NTILES * S, 256, 0, stream>>>(x, W, part, D_DIM / S);
  epilogue<<<N_TOK / 256, 256, 0, stream>>>(part, S, out, p_sum_d, freq, lsesq_d);
  finalize<<<1, 64, 0, stream>>>(p_sum_d, freq, lsesq_d, out + 4 * N_TOK);
}

// Round 4
// 134.976 us; speedup vs baseline: 14.7030x; 1.1056x over previous
//
#include <hip/hip_runtime.h>
#include <hip/hip_bf16.h>
#include <math.h>

#define N_TOK 16384
#define D_DIM 2048
#define E_EXP 64
#define NTILES 256   /* N_TOK / 64 : 64-token tiles */

// global -> LDS direct (16B per lane; LDS dest = wave-uniform base + lane*16)
#define GLDS(gp, lp)                                                        \
  __builtin_amdgcn_global_load_lds(                                         \
      (const __attribute__((address_space(1))) void*)(gp),                  \
      (__attribute__((address_space(3))) void*)(lp), 16, 0, 0)

// ---------------------------------------------------------------------------
// GEMM: part[s][t][e] = sum_{k in split s} x[t][k] * W[e][k]
// grid = NTILES * nsplit, 128 threads (2 waves). Tile: 64 tok x 64 exp,
// thread = 8 tok x 4 exp (acc 32, FMA:LDS-read = 10.7:1, x reads broadcast).
// Staging via global_load_lds, double-buffered; swizzle applied on the
// GLOBAL source address (linear LDS dest), un-swizzled on the LDS read.
// ---------------------------------------------------------------------------
__global__ __launch_bounds__(128)
void router_gemm(const float* __restrict__ x, const float* __restrict__ W,
                 float* __restrict__ part, int kper) {
  __shared__ __align__(16) float s_x[2][64 * 32];
  __shared__ __align__(16) float s_w[2][64 * 32];
  const int tile  = blockIdx.x & (NTILES - 1);
  const int split = blockIdx.x >> 8;
  const int tid  = threadIdx.x;
  const int lane = tid & 63;
  const int w    = tid >> 6;       // wave 0/1
  const int tx   = tid & 15;       // experts 4*tx + j
  const int ty   = tid >> 4;       // tokens 8*i + ty   (ty 0..7 across 2 waves)
  const int k0   = split * kper;
  const int nchunk = kper >> 5;

  // staging lane geometry: lane covers row lr=lane>>3 within an 8-row segment,
  // physical float4-slot lc=lane&7.
  const int lr  = lane >> 3;
  const int lc  = lane & 7;
  const int ls5 = lane >> 5;
  // x swizzle (row&7 == lr for all segments): source slot = lc ^ lr
  const float* xsrc = x + (size_t)(tile * 64 + 32 * w + lr) * D_DIM + k0 +
                      ((lc ^ lr) << 2);
  const float* wsrc = W + (size_t)(32 * w + lr) * D_DIM + k0;

  float acc[8][4];
#pragma unroll
  for (int i = 0; i < 8; ++i)
#pragma unroll
    for (int j = 0; j < 4; ++j) acc[i][j] = 0.f;

#define STAGE(buf, c)                                                        \
  do {                                                                       \
    _Pragma("unroll")                                                        \
    for (int u = 0; u < 4; ++u) {                                            \
      GLDS(xsrc + (size_t)u * 8 * D_DIM + (c) * 32,                          \
           &s_x[buf][w * 1024 + u * 256]);                                   \
      const int qw = lc ^ ((2 * u + ls5) & 7);  /* (row>>2)&7 swizzle */     \
      GLDS(wsrc + (size_t)u * 8 * D_DIM + (c) * 32 + (qw << 2),              \
           &s_w[buf][w * 1024 + u * 256]);                                   \
    }                                                                        \
  } while (0)

  STAGE(0, 0);
  __syncthreads();

  for (int c = 0; c < nchunk; ++c) {
    if (c + 1 < nchunk) STAGE((c + 1) & 1, c + 1);
    const float* px = s_x[c & 1];
    const float* pw = s_w[c & 1];
#pragma unroll
    for (int s = 0; s < 8; ++s) {
      float4 wv[4];
#pragma unroll
      for (int j = 0; j < 4; ++j)   // row 4tx+j, phys slot s ^ ((row>>2)&7)=s^(tx&7)
        wv[j] = *(const float4*)(pw + (4 * tx + j) * 32 + ((s ^ (tx & 7)) << 2));
#pragma unroll
      for (int i = 0; i < 8; ++i) { // row 8i+ty, phys slot s ^ (row&7) = s ^ ty
        float4 xv = *(const float4*)(px + (8 * i + ty) * 32 + ((s ^ ty) << 2));
#pragma unroll
        for (int j = 0; j < 4; ++j)
          acc[i][j] += xv.x * wv[j].x + xv.y * wv[j].y +
                       xv.z * wv[j].z + xv.w * wv[j].w;
      }
    }
    __syncthreads();
  }
#undef STAGE

#pragma unroll
  for (int i = 0; i < 8; ++i) {
    const int t = tile * 64 + 8 * i + ty;
    float4 v = make_float4(acc[i][0], acc[i][1], acc[i][2], acc[i][3]);
    *(float4*)(part + ((size_t)split * N_TOK + t) * 64 + 4 * tx) = v;
  }
}

// ---------------------------------------------------------------------------
// Epilogue: 256 blocks x 64 threads (1 token/thread, one wave per block).
// Per-block partial p_sum / lse^2 stored (no f64 atomic contention);
// freq via fast u32 global atomics.
// ---------------------------------------------------------------------------
__global__ __launch_bounds__(64)
void epilogue(const float* __restrict__ part, int nsplit,
              float* __restrict__ out,
              double* __restrict__ blk_ps,     // [256][64]
              double* __restrict__ blk_z,      // [256]
              unsigned* __restrict__ freq) {
  const int lane = threadIdx.x;                // 0..63
  const int t    = blockIdx.x * 64 + lane;

  float l[64];
  {
    const float* p0 = part + (size_t)t * 64;
#pragma unroll
    for (int q = 0; q < 16; ++q) {
      float4 a = *(const float4*)(p0 + q * 4);
      l[q * 4 + 0] = a.x; l[q * 4 + 1] = a.y;
      l[q * 4 + 2] = a.z; l[q * 4 + 3] = a.w;
    }
  }
  for (int s = 1; s < nsplit; ++s) {
    const float* ps = part + ((size_t)s * N_TOK + t) * 64;
#pragma unroll
    for (int q = 0; q < 16; ++q) {
      float4 a = *(const float4*)(ps + q * 4);
      l[q * 4 + 0] += a.x; l[q * 4 + 1] += a.y;
      l[q * 4 + 2] += a.z; l[q * 4 + 3] += a.w;
    }
  }

  float m = l[0];
#pragma unroll
  for (int e = 1; e < 64; ++e) m = fmaxf(m, l[e]);

  float sum = 0.f;
#pragma unroll
  for (int e = 0; e < 64; ++e) sum += __expf(l[e] - m);
  const float lse = m + __logf(sum);
  const float inv = 1.0f / sum;

  // top-2 scan, strict > keeps lowest index on ties (lax.top_k semantics)
  float v0 = l[0], v1 = -3.402823466e38f;
  int i0 = 0, i1 = 0;
#pragma unroll
  for (int e = 1; e < 64; ++e) {
    float le = l[e];
    bool g0 = le > v0;
    bool g1 = le > v1;
    float nv1 = g0 ? v0 : (g1 ? le : v1);
    int   ni1 = g0 ? i0 : (g1 ? e  : i1);
    float nv0 = g0 ? le : v0;
    int   ni0 = g0 ? e  : i0;
    v0 = nv0; i0 = ni0; v1 = nv1; i1 = ni1;
  }

  float d  = __expf(v1 - v0);
  float g0 = 1.0f / (1.0f + d);
  float g1 = d * g0;

  out[t * 2 + 0] = (float)i0;
  out[t * 2 + 1] = (float)i1;
  out[2 * N_TOK + t * 2 + 0] = g0;
  out[2 * N_TOK + t * 2 + 1] = g1;

  // freq histogram: LDS within block, one u32 atomic per expert per block
  __shared__ unsigned hist[64];
  hist[lane] = 0u;
  __syncthreads();
  atomicAdd(&hist[i0], 1u);
  atomicAdd(&hist[i1], 1u);
  __syncthreads();
  if (hist[lane]) atomicAdd(&freq[lane], hist[lane]);

  // p_sum: per-expert wave butterfly; lane e ends holding block-sum for e
  float myps = 0.f;
#pragma unroll
  for (int e = 0; e < 64; ++e) {
    float v = __expf(l[e] - m) * inv;
    v += __shfl_xor(v, 32, 64);
    v += __shfl_xor(v, 16, 64);
    v += __shfl_xor(v, 8, 64);
    v += __shfl_xor(v, 4, 64);
    v += __shfl_xor(v, 2, 64);
    v += __shfl_xor(v, 1, 64);
    myps = (lane == e) ? v : myps;
  }
  blk_ps[(size_t)blockIdx.x * 64 + lane] = (double)myps;

  float z = lse * lse;
  z += __shfl_xor(z, 32, 64);
  z += __shfl_xor(z, 16, 64);
  z += __shfl_xor(z, 8, 64);
  z += __shfl_xor(z, 4, 64);
  z += __shfl_xor(z, 2, 64);
  z += __shfl_xor(z, 1, 64);
  if (lane == 0) blk_z[blockIdx.x] = (double)z;
}

// ---------------------------------------------------------------------------
// Finalize: sum per-block partials, switchloss + 0.1*z_loss (1 block, 64 thr)
// ---------------------------------------------------------------------------
__global__ void finalize(const double* __restrict__ blk_ps,
                         const double* __restrict__ blk_z,
                         const unsigned* __restrict__ freq,
                         float* __restrict__ out_loss) {
  const int lane = threadIdx.x;
  double p = 0.0;
  for (int b = 0; b < 256; ++b) p += blk_ps[(size_t)b * 64 + lane];
  double zt = 0.0;
#pragma unroll
  for (int b = 0; b < 4; ++b) zt += blk_z[lane * 4 + b];
#pragma unroll
  for (int off = 32; off >= 1; off >>= 1) zt += __shfl_xor(zt, off, 64);

  double f = (double)freq[lane];
  double pa = fabs(p);
  double fa = fabs(f);
#pragma unroll
  for (int off = 32; off >= 1; off >>= 1) {
    pa += __shfl_xor(pa, off, 64);
    fa += __shfl_xor(fa, off, 64);
  }
  pa = pa > 1e-12 ? pa : 1e-12;
  fa = fa > 1e-12 ? fa : 1e-12;

  double s = (p / pa) * (f / fa);
#pragma unroll
  for (int off = 32; off >= 1; off >>= 1) s += __shfl_xor(s, off, 64);

  if (lane == 0) {
    double switchloss = 64.0 * s;
    double z_loss = zt / (double)N_TOK;
    out_loss[0] = (float)(switchloss + 0.1 * z_loss);
  }
}

extern "C" void kernel_launch(void* const* d_in, const int* in_sizes, int n_in,
                              void* d_out, int out_size, void* d_ws, size_t ws_size,
                              hipStream_t stream) {
  const float* x = (const float*)d_in[0];
  const float* W = (const float*)d_in[1];
  float* out = (float*)d_out;

  const size_t partB = (size_t)N_TOK * 64 * 4;  // 4 MB per split
  int S = 4;
  while (S > 1 && (size_t)S * partB + (1 << 20) > ws_size) S >>= 1;

  float* part = (float*)d_ws;
  size_t tail = ((size_t)S * partB + 511) & ~(size_t)511;
  double* blk_ps = (double*)((char*)d_ws + tail);        // 256*64*8 = 128KB
  double* blk_z  = blk_ps + 256 * 64;                    // 2KB
  unsigned* freq = (unsigned*)(blk_z + 256);             // 256B

  hipMemsetAsync(freq, 0, 64 * sizeof(unsigned), stream);

  router_gemm<<<NTILES * S, 128, 0, stream>>>(x, W, part, D_DIM / S);
  epilogue<<<N_TOK / 64, 64, 0, stream>>>(part, S, out, blk_ps, blk_z, freq);
  finalize<<<1, 64, 0, stream>>>(blk_ps, blk_z, freq, out + 4 * N_TOK);
}

// Round 5
// 120.598 us; speedup vs baseline: 16.4560x; 1.1192x over previous
//
#include <hip/hip_runtime.h>
#include <hip/hip_bf16.h>
#include <math.h>

#define N_TOK 16384
#define D_DIM 2048
#define E_EXP 64
#define NTILES 256   /* N_TOK / 64 : 64-token tiles */

// global -> LDS direct (16B per lane; LDS dest = wave-uniform base + lane*16)
#define GLDS(gp, lp)                                                        \
  __builtin_amdgcn_global_load_lds(                                         \
      (const __attribute__((address_space(1))) void*)(gp),                  \
      (__attribute__((address_space(3))) void*)(lp), 16, 0, 0)

// ---------------------------------------------------------------------------
// GEMM: part[s][t][e] = sum_{k in split s} x[t][k] * W[e][k]
// grid = NTILES * nsplit, 128 threads (2 waves). Tile: 64 tok x 64 exp,
// thread = 8 tok x 4 exp. Staging via global_load_lds (swizzle on the
// GLOBAL source, linear LDS dest). Inner loop: per s-slice only 2 v_xor
// compute both swizzled LDS addresses (slot bits [6:4] don't overlap row
// bits, so addr = base ^ (s<<4)); all ds_read_b128 use immediate offsets;
// accumulation written as separate += to force v_fmac chains.
// __launch_bounds__(128,3): VGPR cap 170 (demand ~120, no spill; R2's
// (256,4)->64-cap lesson: never cap below live demand).
// ---------------------------------------------------------------------------
__global__ __launch_bounds__(128, 3)
void router_gemm(const float* __restrict__ x, const float* __restrict__ W,
                 float* __restrict__ part, int kper) {
  __shared__ __align__(16) float s_x[2][64 * 32];
  __shared__ __align__(16) float s_w[2][64 * 32];
  const int tile  = blockIdx.x & (NTILES - 1);
  const int split = blockIdx.x >> 8;
  const int tid  = threadIdx.x;
  const int lane = tid & 63;
  const int w    = tid >> 6;       // wave 0/1
  const int tx   = tid & 15;       // experts 4*tx + j
  const int ty   = tid >> 4;       // tokens 8*i + ty (ty 0..7 across 2 waves)
  const int k0   = split * kper;
  const int nchunk = kper >> 5;

  // staging lane geometry
  const int lr  = lane >> 3;
  const int lc  = lane & 7;
  const int ls5 = lane >> 5;
  const float* xsrc = x + (size_t)(tile * 64 + 32 * w + lr) * D_DIM + k0 +
                      ((lc ^ lr) << 2);
  const float* wsrc = W + (size_t)(32 * w + lr) * D_DIM + k0;

  float acc[8][4];
#pragma unroll
  for (int i = 0; i < 8; ++i)
#pragma unroll
    for (int j = 0; j < 4; ++j) acc[i][j] = 0.f;

#define STAGE(buf, c)                                                        \
  do {                                                                       \
    _Pragma("unroll")                                                        \
    for (int u = 0; u < 4; ++u) {                                            \
      GLDS(xsrc + (size_t)u * 8 * D_DIM + (c) * 32,                          \
           &s_x[buf][w * 1024 + u * 256]);                                   \
      const int qw = lc ^ ((2 * u + ls5) & 7);  /* (row>>2)&7 swizzle */     \
      GLDS(wsrc + (size_t)u * 8 * D_DIM + (c) * 32 + (qw << 2),              \
           &s_w[buf][w * 1024 + u * 256]);                                   \
    }                                                                        \
  } while (0)

  STAGE(0, 0);
  __syncthreads();

  // byte-offset bases inside LDS tiles; slot bits [6:4], row bits >=7
  const int xb0 = ty * 128 + (ty << 4);        // row ty, swizzle const c=ty
  const int wb0 = tx * 512 + ((tx & 7) << 4);  // row 4tx, swizzle const tx&7

  for (int c = 0; c < nchunk; ++c) {
    if (c + 1 < nchunk) STAGE((c + 1) & 1, c + 1);
    const char* pxc = (const char*)&s_x[c & 1][0];
    const char* pwc = (const char*)&s_w[c & 1][0];
#pragma unroll
    for (int s = 0; s < 8; ++s) {
      const int xo = xb0 ^ (s << 4);   // 1 v_xor: x slot = s ^ ty
      const int wo = wb0 ^ (s << 4);   // 1 v_xor: w slot = s ^ (tx&7)
      float4 wv[4];
#pragma unroll
      for (int j = 0; j < 4; ++j)
        wv[j] = *(const float4*)(pwc + wo + j * 128);   // imm offset j*128
#pragma unroll
      for (int i = 0; i < 8; ++i) {
        float4 xv = *(const float4*)(pxc + xo + i * 1024);  // imm i*1024
#pragma unroll
        for (int j = 0; j < 4; ++j) {
          acc[i][j] += xv.x * wv[j].x;
          acc[i][j] += xv.y * wv[j].y;
          acc[i][j] += xv.z * wv[j].z;
          acc[i][j] += xv.w * wv[j].w;
        }
      }
    }
    __syncthreads();
  }
#undef STAGE

#pragma unroll
  for (int i = 0; i < 8; ++i) {
    const int t = tile * 64 + 8 * i + ty;
    float4 v = make_float4(acc[i][0], acc[i][1], acc[i][2], acc[i][3]);
    *(float4*)(part + ((size_t)split * N_TOK + t) * 64 + 4 * tx) = v;
  }
}

// ---------------------------------------------------------------------------
// Epilogue: 256 blocks x 64 threads (1 token/thread, one wave per block).
// ---------------------------------------------------------------------------
__global__ __launch_bounds__(64)
void epilogue(const float* __restrict__ part, int nsplit,
              float* __restrict__ out,
              double* __restrict__ blk_ps,     // [256][64]
              double* __restrict__ blk_z,      // [256]
              unsigned* __restrict__ freq) {
  const int lane = threadIdx.x;                // 0..63
  const int t    = blockIdx.x * 64 + lane;

  float l[64];
  {
    const float* p0 = part + (size_t)t * 64;
#pragma unroll
    for (int q = 0; q < 16; ++q) {
      float4 a = *(const float4*)(p0 + q * 4);
      l[q * 4 + 0] = a.x; l[q * 4 + 1] = a.y;
      l[q * 4 + 2] = a.z; l[q * 4 + 3] = a.w;
    }
  }
  for (int s = 1; s < nsplit; ++s) {
    const float* ps = part + ((size_t)s * N_TOK + t) * 64;
#pragma unroll
    for (int q = 0; q < 16; ++q) {
      float4 a = *(const float4*)(ps + q * 4);
      l[q * 4 + 0] += a.x; l[q * 4 + 1] += a.y;
      l[q * 4 + 2] += a.z; l[q * 4 + 3] += a.w;
    }
  }

  float m = l[0];
#pragma unroll
  for (int e = 1; e < 64; ++e) m = fmaxf(m, l[e]);

  float sum = 0.f;
#pragma unroll
  for (int e = 0; e < 64; ++e) sum += __expf(l[e] - m);
  const float lse = m + __logf(sum);
  const float inv = 1.0f / sum;

  // top-2 scan, strict > keeps lowest index on ties (lax.top_k semantics)
  float v0 = l[0], v1 = -3.402823466e38f;
  int i0 = 0, i1 = 0;
#pragma unroll
  for (int e = 1; e < 64; ++e) {
    float le = l[e];
    bool g0 = le > v0;
    bool g1 = le > v1;
    float nv1 = g0 ? v0 : (g1 ? le : v1);
    int   ni1 = g0 ? i0 : (g1 ? e  : i1);
    float nv0 = g0 ? le : v0;
    int   ni0 = g0 ? e  : i0;
    v0 = nv0; i0 = ni0; v1 = nv1; i1 = ni1;
  }

  float d  = __expf(v1 - v0);
  float g0 = 1.0f / (1.0f + d);
  float g1 = d * g0;

  out[t * 2 + 0] = (float)i0;
  out[t * 2 + 1] = (float)i1;
  out[2 * N_TOK + t * 2 + 0] = g0;
  out[2 * N_TOK + t * 2 + 1] = g1;

  // freq histogram: LDS within block, one u32 atomic per expert per block
  __shared__ unsigned hist[64];
  hist[lane] = 0u;
  __syncthreads();
  atomicAdd(&hist[i0], 1u);
  atomicAdd(&hist[i1], 1u);
  __syncthreads();
  if (hist[lane]) atomicAdd(&freq[lane], hist[lane]);

  // p_sum: per-expert wave butterfly; lane e ends holding block-sum for e
  float myps = 0.f;
#pragma unroll
  for (int e = 0; e < 64; ++e) {
    float v = __expf(l[e] - m) * inv;
    v += __shfl_xor(v, 32, 64);
    v += __shfl_xor(v, 16, 64);
    v += __shfl_xor(v, 8, 64);
    v += __shfl_xor(v, 4, 64);
    v += __shfl_xor(v, 2, 64);
    v += __shfl_xor(v, 1, 64);
    myps = (lane == e) ? v : myps;
  }
  blk_ps[(size_t)blockIdx.x * 64 + lane] = (double)myps;

  float z = lse * lse;
  z += __shfl_xor(z, 32, 64);
  z += __shfl_xor(z, 16, 64);
  z += __shfl_xor(z, 8, 64);
  z += __shfl_xor(z, 4, 64);
  z += __shfl_xor(z, 2, 64);
  z += __shfl_xor(z, 1, 64);
  if (lane == 0) blk_z[blockIdx.x] = (double)z;
}

// ---------------------------------------------------------------------------
// Finalize: sum per-block partials, switchloss + 0.1*z_loss (1 block, 64 thr)
// ---------------------------------------------------------------------------
__global__ void finalize(const double* __restrict__ blk_ps,
                         const double* __restrict__ blk_z,
                         const unsigned* __restrict__ freq,
                         float* __restrict__ out_loss) {
  const int lane = threadIdx.x;
  double p = 0.0;
  for (int b = 0; b < 256; ++b) p += blk_ps[(size_t)b * 64 + lane];
  double zt = 0.0;
#pragma unroll
  for (int b = 0; b < 4; ++b) zt += blk_z[lane * 4 + b];
#pragma unroll
  for (int off = 32; off >= 1; off >>= 1) zt += __shfl_xor(zt, off, 64);

  double f = (double)freq[lane];
  double pa = fabs(p);
  double fa = fabs(f);
#pragma unroll
  for (int off = 32; off >= 1; off >>= 1) {
    pa += __shfl_xor(pa, off, 64);
    fa += __shfl_xor(fa, off, 64);
  }
  pa = pa > 1e-12 ? pa : 1e-12;
  fa = fa > 1e-12 ? fa : 1e-12;

  double s = (p / pa) * (f / fa);
#pragma unroll
  for (int off = 32; off >= 1; off >>= 1) s += __shfl_xor(s, off, 64);

  if (lane == 0) {
    double switchloss = 64.0 * s;
    double z_loss = zt / (double)N_TOK;
    out_loss[0] = (float)(switchloss + 0.1 * z_loss);
  }
}

extern "C" void kernel_launch(void* const* d_in, const int* in_sizes, int n_in,
                              void* d_out, int out_size, void* d_ws, size_t ws_size,
                              hipStream_t stream) {
  const float* x = (const float*)d_in[0];
  const float* W = (const float*)d_in[1];
  float* out = (float*)d_out;

  const size_t partB = (size_t)N_TOK * 64 * 4;  // 4 MB per split
  int S = 4;
  while (S > 1 && (size_t)S * partB + (1 << 20) > ws_size) S >>= 1;

  float* part = (float*)d_ws;
  size_t tail = ((size_t)S * partB + 511) & ~(size_t)511;
  double* blk_ps = (double*)((char*)d_ws + tail);        // 256*64*8 = 128KB
  double* blk_z  = blk_ps + 256 * 64;                    // 2KB
  unsigned* freq = (unsigned*)(blk_z + 256);             // 256B

  hipMemsetAsync(freq, 0, 64 * sizeof(unsigned), stream);

  router_gemm<<<NTILES * S, 128, 0, stream>>>(x, W, part, D_DIM / S);
  epilogue<<<N_TOK / 64, 64, 0, stream>>>(part, S, out, blk_ps, blk_z, freq);
  finalize<<<1, 64, 0, stream>>>(blk_ps, blk_z, freq, out + 4 * N_TOK);
}

// Round 6
// 99.228 us; speedup vs baseline: 19.9999x; 1.2154x over previous
//
#include <hip/hip_runtime.h>
#include <hip/hip_bf16.h>
#include <math.h>

#define N_TOK 16384
#define D_DIM 2048
#define E_EXP 64
#define NT128 128    /* N_TOK / 128 : 128-token tiles */

// global -> LDS direct (16B per lane; LDS dest = wave-uniform base + lane*16)
#define GLDS(gp, lp)                                                        \
  __builtin_amdgcn_global_load_lds(                                         \
      (const __attribute__((address_space(1))) void*)(gp),                  \
      (__attribute__((address_space(3))) void*)(lp), 16, 0, 0)

// ---------------------------------------------------------------------------
// GEMM: part[s][t][e] = sum_{k in split s} x[t][k] * W[e][k]
// grid = NT128 * nsplit, 128 threads (2 waves). Block tile: 128 tok x 64 exp.
// Thread tile: 8 tok (r = ty+16i) x 8 consecutive exp (e = 8tx+j).
// Per s-slice: 16 ds_read_b128 per 256 v_fmac -> VALU-dominant (R5 was 12/128
// = LDS-pipe-bound). K-chunk = 16 (4 float4 slots), LDS 24KB, double-buffered
// via global_load_lds: linear LDS dest, swizzle folded into the GLOBAL source
// column (x: slot^=row&3, w: slot^=(row>>3)&3); reads un-swizzle with 1 v_xor
// (slot bits [4:5] don't overlap row bits). All LDS reads 2-way max (free).
// ---------------------------------------------------------------------------
__global__ __launch_bounds__(128)
void router_gemm(const float* __restrict__ x, const float* __restrict__ W,
                 float* __restrict__ part, int kper) {
  __shared__ __align__(16) float s_x[2][128 * 16];
  __shared__ __align__(16) float s_w[2][64 * 16];
  const int tile  = blockIdx.x & (NT128 - 1);
  const int split = blockIdx.x >> 7;
  const int tid  = threadIdx.x;
  const int lane = tid & 63;
  const int w    = tid >> 6;      // wave 0/1
  const int tx   = tid & 7;       // experts 8*tx + j
  const int ty   = tid >> 3;      // tokens ty + 16*i  (ty 0..15)
  const int T0   = tile * 128;
  const int k0   = split * kper;
  const int nchunk = kper >> 4;   // K chunks of 16

  // staging lane geometry: lane l covers row (l>>2) in a 16-row segment,
  // phys float4-slot lc = l&3.
  const int lr = lane >> 2;       // 0..15
  const int lc = lane & 3;
  // x source: row = 64w + 16u + lr; swz = row&3 = lr&3
  const float* xl = x + (size_t)(T0 + 64 * w + lr) * D_DIM + k0 +
                    ((lc ^ (lr & 3)) << 2);
  // w source: row = 32w + 16u + lr; swz = (row>>3)&3 = (4w + 2u + (lane>>5))&3
  const int ls5 = lane >> 5;
  const float* wl0 = W + (size_t)(32 * w + lr) * D_DIM + k0 +
                     ((lc ^ ((2 * 0 + ls5) & 3)) << 2);
  const float* wl1 = W + (size_t)(32 * w + 16 + lr) * D_DIM + k0 +
                     ((lc ^ ((2 * 1 + ls5) & 3)) << 2);

  float acc[8][8];
#pragma unroll
  for (int i = 0; i < 8; ++i)
#pragma unroll
    for (int j = 0; j < 8; ++j) acc[i][j] = 0.f;

#define STAGE(buf, c)                                                        \
  do {                                                                       \
    _Pragma("unroll")                                                        \
    for (int u = 0; u < 4; ++u)                                              \
      GLDS(xl + (size_t)u * 16 * D_DIM + (c) * 16,                           \
           &s_x[buf][(64 * w + 16 * u) * 16]);                               \
    GLDS(wl0 + (c) * 16, &s_w[buf][(32 * w) * 16]);                          \
    GLDS(wl1 + (c) * 16, &s_w[buf][(32 * w + 16) * 16]);                     \
  } while (0)

  STAGE(0, 0);
  __syncthreads();

  // byte bases; slot bits [4:5], x row bits >=6, w row bits >=6
  const int xb = ty * 64 + ((ty & 3) << 4);         // row ty, swz const ty&3
  const int wb = tx * 512 + ((tx & 3) << 4);        // row 8tx, swz const tx&3

  for (int c = 0; c < nchunk; ++c) {
    if (c + 1 < nchunk) STAGE((c + 1) & 1, c + 1);
    const char* pxc = (const char*)&s_x[c & 1][0];
    const char* pwc = (const char*)&s_w[c & 1][0];
#pragma unroll
    for (int s = 0; s < 4; ++s) {
      const int xo = xb ^ (s << 4);
      const int wo = wb ^ (s << 4);
      float4 wv[8];
#pragma unroll
      for (int j = 0; j < 8; ++j)
        wv[j] = *(const float4*)(pwc + wo + j * 64);       // imm j*64
#pragma unroll
      for (int i = 0; i < 8; ++i) {
        float4 xv = *(const float4*)(pxc + xo + i * 1024); // imm i*1024
#pragma unroll
        for (int j = 0; j < 8; ++j) {
          acc[i][j] += xv.x * wv[j].x;
          acc[i][j] += xv.y * wv[j].y;
          acc[i][j] += xv.z * wv[j].z;
          acc[i][j] += xv.w * wv[j].w;
        }
      }
    }
    __syncthreads();
  }
#undef STAGE

#pragma unroll
  for (int i = 0; i < 8; ++i) {
    const int t = T0 + ty + 16 * i;
    float* p = part + ((size_t)split * N_TOK + t) * 64 + 8 * tx;
    *(float4*)(p)     = make_float4(acc[i][0], acc[i][1], acc[i][2], acc[i][3]);
    *(float4*)(p + 4) = make_float4(acc[i][4], acc[i][5], acc[i][6], acc[i][7]);
  }
}

// ---------------------------------------------------------------------------
// Epilogue: 256 blocks x 64 threads (1 token/thread, one wave per block).
// ---------------------------------------------------------------------------
__global__ __launch_bounds__(64)
void epilogue(const float* __restrict__ part, int nsplit,
              float* __restrict__ out,
              double* __restrict__ blk_ps,     // [256][64]
              double* __restrict__ blk_z,      // [256]
              unsigned* __restrict__ freq) {
  const int lane = threadIdx.x;                // 0..63
  const int t    = blockIdx.x * 64 + lane;

  float l[64];
  {
    const float* p0 = part + (size_t)t * 64;
#pragma unroll
    for (int q = 0; q < 16; ++q) {
      float4 a = *(const float4*)(p0 + q * 4);
      l[q * 4 + 0] = a.x; l[q * 4 + 1] = a.y;
      l[q * 4 + 2] = a.z; l[q * 4 + 3] = a.w;
    }
  }
  for (int s = 1; s < nsplit; ++s) {
    const float* ps = part + ((size_t)s * N_TOK + t) * 64;
#pragma unroll
    for (int q = 0; q < 16; ++q) {
      float4 a = *(const float4*)(ps + q * 4);
      l[q * 4 + 0] += a.x; l[q * 4 + 1] += a.y;
      l[q * 4 + 2] += a.z; l[q * 4 + 3] += a.w;
    }
  }

  float m = l[0];
#pragma unroll
  for (int e = 1; e < 64; ++e) m = fmaxf(m, l[e]);

  float sum = 0.f;
#pragma unroll
  for (int e = 0; e < 64; ++e) sum += __expf(l[e] - m);
  const float lse = m + __logf(sum);
  const float inv = 1.0f / sum;

  // top-2 scan, strict > keeps lowest index on ties (lax.top_k semantics)
  float v0 = l[0], v1 = -3.402823466e38f;
  int i0 = 0, i1 = 0;
#pragma unroll
  for (int e = 1; e < 64; ++e) {
    float le = l[e];
    bool g0 = le > v0;
    bool g1 = le > v1;
    float nv1 = g0 ? v0 : (g1 ? le : v1);
    int   ni1 = g0 ? i0 : (g1 ? e  : i1);
    float nv0 = g0 ? le : v0;
    int   ni0 = g0 ? e  : i0;
    v0 = nv0; i0 = ni0; v1 = nv1; i1 = ni1;
  }

  float d  = __expf(v1 - v0);
  float g0 = 1.0f / (1.0f + d);
  float g1 = d * g0;

  out[t * 2 + 0] = (float)i0;
  out[t * 2 + 1] = (float)i1;
  out[2 * N_TOK + t * 2 + 0] = g0;
  out[2 * N_TOK + t * 2 + 1] = g1;

  // freq histogram: LDS within block, one u32 atomic per expert per block
  __shared__ unsigned hist[64];
  hist[lane] = 0u;
  __syncthreads();
  atomicAdd(&hist[i0], 1u);
  atomicAdd(&hist[i1], 1u);
  __syncthreads();
  if (hist[lane]) atomicAdd(&freq[lane], hist[lane]);

  // p_sum: per-expert wave butterfly; lane e ends holding block-sum for e
  float myps = 0.f;
#pragma unroll
  for (int e = 0; e < 64; ++e) {
    float v = __expf(l[e] - m) * inv;
    v += __shfl_xor(v, 32, 64);
    v += __shfl_xor(v, 16, 64);
    v += __shfl_xor(v, 8, 64);
    v += __shfl_xor(v, 4, 64);
    v += __shfl_xor(v, 2, 64);
    v += __shfl_xor(v, 1, 64);
    myps = (lane == e) ? v : myps;
  }
  blk_ps[(size_t)blockIdx.x * 64 + lane] = (double)myps;

  float z = lse * lse;
  z += __shfl_xor(z, 32, 64);
  z += __shfl_xor(z, 16, 64);
  z += __shfl_xor(z, 8, 64);
  z += __shfl_xor(z, 4, 64);
  z += __shfl_xor(z, 2, 64);
  z += __shfl_xor(z, 1, 64);
  if (lane == 0) blk_z[blockIdx.x] = (double)z;
}

// ---------------------------------------------------------------------------
// Finalize: sum per-block partials, switchloss + 0.1*z_loss (1 block, 64 thr)
// ---------------------------------------------------------------------------
__global__ void finalize(const double* __restrict__ blk_ps,
                         const double* __restrict__ blk_z,
                         const unsigned* __restrict__ freq,
                         float* __restrict__ out_loss) {
  const int lane = threadIdx.x;
  double p = 0.0;
  for (int b = 0; b < 256; ++b) p += blk_ps[(size_t)b * 64 + lane];
  double zt = 0.0;
#pragma unroll
  for (int b = 0; b < 4; ++b) zt += blk_z[lane * 4 + b];
#pragma unroll
  for (int off = 32; off >= 1; off >>= 1) zt += __shfl_xor(zt, off, 64);

  double f = (double)freq[lane];
  double pa = fabs(p);
  double fa = fabs(f);
#pragma unroll
  for (int off = 32; off >= 1; off >>= 1) {
    pa += __shfl_xor(pa, off, 64);
    fa += __shfl_xor(fa, off, 64);
  }
  pa = pa > 1e-12 ? pa : 1e-12;
  fa = fa > 1e-12 ? fa : 1e-12;

  double s = (p / pa) * (f / fa);
#pragma unroll
  for (int off = 32; off >= 1; off >>= 1) s += __shfl_xor(s, off, 64);

  if (lane == 0) {
    double switchloss = 64.0 * s;
    double z_loss = zt / (double)N_TOK;
    out_loss[0] = (float)(switchloss + 0.1 * z_loss);
  }
}

extern "C" void kernel_launch(void* const* d_in, const int* in_sizes, int n_in,
                              void* d_out, int out_size, void* d_ws, size_t ws_size,
                              hipStream_t stream) {
  const float* x = (const float*)d_in[0];
  const float* W = (const float*)d_in[1];
  float* out = (float*)d_out;

  const size_t partB = (size_t)N_TOK * 64 * 4;  // 4 MB per split
  int S = 8;                                    // grid 1024 -> 8 waves/CU
  while (S > 1 && (size_t)S * partB + (1 << 20) > ws_size) S >>= 1;

  float* part = (float*)d_ws;
  size_t tail = ((size_t)S * partB + 511) & ~(size_t)511;
  double* blk_ps = (double*)((char*)d_ws + tail);        // 256*64*8 = 128KB
  double* blk_z  = blk_ps + 256 * 64;                    // 2KB
  unsigned* freq = (unsigned*)(blk_z + 256);             // 256B

  hipMemsetAsync(freq, 0, 64 * sizeof(unsigned), stream);

  router_gemm<<<NT128 * S, 128, 0, stream>>>(x, W, part, D_DIM / S);
  epilogue<<<N_TOK / 64, 64, 0, stream>>>(part, S, out, blk_ps, blk_z, freq);
  finalize<<<1, 64, 0, stream>>>(blk_ps, blk_z, freq, out + 4 * N_TOK);
}

// Round 7
// 62.781 us; speedup vs baseline: 31.6108x; 1.5805x over previous
//
#include <hip/hip_runtime.h>
#include <hip/hip_bf16.h>
#include <math.h>

#define N_TOK 16384
#define D_DIM 2048
#define E_EXP 64
#define SPLIT 4
#define KPER  (D_DIM / SPLIT)   /* 512 */
#define NCH   (KPER / 32)       /* 16 K-chunks per block */
#define NTILE (N_TOK / 64)      /* 256 token tiles */

typedef __attribute__((ext_vector_type(8))) short bf16x8;
typedef __attribute__((ext_vector_type(4))) float f32x4;
typedef __attribute__((ext_vector_type(4))) unsigned int u32x4;

// ---------------------------------------------------------------------------
// pack_w: W fp32 [64][2048] -> exact 3-limb bf16 split, frag-ordered:
// Wp[chunk c][kgroup g][tau][e][8 bf16]  (tau 0/1/2 = hi/mid/lo limb)
// Split is EXACT: h|m|l = top|next|last 8 significand bits (masking; the
// subtractions are exact in fp32), so x*w error comes only from the dropped
// ml/lm/ll cross terms (<= ~2^-23 rel) -- below fp32 GEMM summation noise.
// ---------------------------------------------------------------------------
__global__ void pack_w(const float* __restrict__ W,
                       unsigned short* __restrict__ Wp) {
  const int T = blockIdx.x * 256 + threadIdx.x;   // 16384 = 64c * 4g * 64e
  const int e = T & 63, g = (T >> 6) & 3, c = T >> 8;
  const float* src = W + (size_t)e * D_DIM + c * 32 + g * 8;
  float4 v0 = *(const float4*)src;
  float4 v1 = *(const float4*)(src + 4);
  float vv[8] = {v0.x, v0.y, v0.z, v0.w, v1.x, v1.y, v1.z, v1.w};
  unsigned hu[8], mu[8], lu[8];
#pragma unroll
  for (int j = 0; j < 8; ++j) {
    unsigned u = __float_as_uint(vv[j]);
    unsigned a = u & 0xffff0000u;
    float r = vv[j] - __uint_as_float(a);
    unsigned b = __float_as_uint(r) & 0xffff0000u;
    float r2 = r - __uint_as_float(b);
    unsigned d = __float_as_uint(r2) & 0xffff0000u;
    hu[j] = a; mu[j] = b; lu[j] = d;
  }
  unsigned ph[4], pm[4], pl[4];
#pragma unroll
  for (int q = 0; q < 4; ++q) {     // ascending k pairs: lo in low 16
    ph[q] = (hu[2 * q] >> 16) | (hu[2 * q + 1] & 0xffff0000u);
    pm[q] = (mu[2 * q] >> 16) | (mu[2 * q + 1] & 0xffff0000u);
    pl[q] = (lu[2 * q] >> 16) | (lu[2 * q + 1] & 0xffff0000u);
  }
  const size_t base = (size_t)c * 6144 + g * 1536 + e * 8;  // ushort units
  *(u32x4*)(Wp + base)        = *(u32x4*)ph;   // tau 0
  *(u32x4*)(Wp + base + 512)  = *(u32x4*)pm;   // tau 1
  *(u32x4*)(Wp + base + 1024) = *(u32x4*)pl;   // tau 2
}

// ---------------------------------------------------------------------------
// GEMM via mfma_f32_16x16x32_bf16, 6-term limb products.
// grid = NTILE*SPLIT = 1024 blocks, 256 thr (4 waves). Block tile 64tok x
// 64exp; wave = (tok-half, exp-half) -> 2x2 16x16 MFMA tiles, 6 terms = 24
// MFMA per 32-K chunk. x converted to 3 bf16 LDS planes per chunk (dbuf,
// 1 barrier/chunk); W limbs read as B-frags directly from L2 (packed).
// ---------------------------------------------------------------------------
__global__ __launch_bounds__(256)
void router_gemm(const float* __restrict__ x,
                 const unsigned short* __restrict__ Wp,
                 float* __restrict__ part) {
  // LDS: [2 buf][3 tau][64 rows][32 k] bf16 = 24 KB
  __shared__ __align__(16) unsigned short s_x[2 * 3 * 64 * 32];
  const int tid  = threadIdx.x;
  const int lane = tid & 63;
  const int w    = tid >> 6;
  const int th   = w >> 1;            // token half (0/1)
  const int eh   = w & 1;             // expert half (0/1)
  const int tile  = blockIdx.x & (NTILE - 1);
  const int split = blockIdx.x >> 8;
  const int T0 = tile * 64;
  const int k0 = split * KPER;

  // conversion: thread covers row crow, k-group ckg (8 floats/chunk)
  const int crow = tid >> 2;
  const int ckg  = tid & 3;
  const float* xg = x + (size_t)(T0 + crow) * D_DIM + k0 + ckg * 8;
  const int wbase = crow * 32 + ckg * 8;              // ushort idx in a plane

  // A-frag read base: row = th*32 + (lane&15), kgroup g = lane>>4
  const int abase = (th * 32 + (lane & 15)) * 32 + (lane >> 4) * 8;
  // B-frag lane offset: g*1536 + e*8 (ushort), e = eh*32 + nt*16 + (lane&15)
  const int bl = (lane >> 4) * 1536 + (eh * 32 + (lane & 15)) * 8;

  f32x4 acc[2][2];
#pragma unroll
  for (int i = 0; i < 2; ++i)
#pragma unroll
    for (int j = 0; j < 2; ++j) acc[i][j] = (f32x4)0.f;

#define CVT_WRITE(BUF, V0, V1)                                              \
  do {                                                                      \
    float vv[8] = {V0.x, V0.y, V0.z, V0.w, V1.x, V1.y, V1.z, V1.w};         \
    unsigned hu[8], mu[8], lu[8];                                           \
    _Pragma("unroll") for (int j = 0; j < 8; ++j) {                         \
      unsigned u = __float_as_uint(vv[j]);                                  \
      unsigned a = u & 0xffff0000u;                                         \
      float r = vv[j] - __uint_as_float(a);                                 \
      unsigned b = __float_as_uint(r) & 0xffff0000u;                        \
      float r2 = r - __uint_as_float(b);                                    \
      unsigned d = __float_as_uint(r2) & 0xffff0000u;                       \
      hu[j] = a; mu[j] = b; lu[j] = d;                                      \
    }                                                                       \
    unsigned ph[4], pm[4], pl[4];                                           \
    _Pragma("unroll") for (int q = 0; q < 4; ++q) {                         \
      ph[q] = (hu[2 * q] >> 16) | (hu[2 * q + 1] & 0xffff0000u);            \
      pm[q] = (mu[2 * q] >> 16) | (mu[2 * q + 1] & 0xffff0000u);            \
      pl[q] = (lu[2 * q] >> 16) | (lu[2 * q + 1] & 0xffff0000u);            \
    }                                                                       \
    *(u32x4*)&s_x[(BUF) * 6144 + 0 * 2048 + wbase] = *(u32x4*)ph;           \
    *(u32x4*)&s_x[(BUF) * 6144 + 1 * 2048 + wbase] = *(u32x4*)pm;           \
    *(u32x4*)&s_x[(BUF) * 6144 + 2 * 2048 + wbase] = *(u32x4*)pl;           \
  } while (0)

  // prolog: chunk 0 -> buf 0; prefetch chunk 1 into regs
  float4 rx0 = *(const float4*)xg;
  float4 rx1 = *(const float4*)(xg + 4);
  CVT_WRITE(0, rx0, rx1);
  rx0 = *(const float4*)(xg + 32);
  rx1 = *(const float4*)(xg + 36);
  __syncthreads();

  const unsigned short* bp = Wp + (size_t)(split * NCH) * 6144 + bl;

#pragma unroll 1
  for (int c = 0; c < NCH; ++c) {
    const int buf = c & 1;
    if (c + 1 < NCH) CVT_WRITE(buf ^ 1, rx0, rx1);   // regs hold chunk c+1
    if (c + 2 < NCH) {                               // prefetch chunk c+2
      rx0 = *(const float4*)(xg + (c + 2) * 32);
      rx1 = *(const float4*)(xg + (c + 2) * 32 + 4);
    }
    // B-frags for chunk c (L2-resident packed W), imm-offset loads
    bf16x8 B0h = *(const bf16x8*)(bp);
    bf16x8 B0m = *(const bf16x8*)(bp + 512);
    bf16x8 B0l = *(const bf16x8*)(bp + 1024);
    bf16x8 B1h = *(const bf16x8*)(bp + 128);
    bf16x8 B1m = *(const bf16x8*)(bp + 128 + 512);
    bf16x8 B1l = *(const bf16x8*)(bp + 128 + 1024);
    // A-frags from LDS
    const unsigned short* ab = &s_x[buf * 6144 + abase];
    bf16x8 A0h = *(const bf16x8*)(ab);
    bf16x8 A0m = *(const bf16x8*)(ab + 2048);
    bf16x8 A0l = *(const bf16x8*)(ab + 4096);
    bf16x8 A1h = *(const bf16x8*)(ab + 512);
    bf16x8 A1m = *(const bf16x8*)(ab + 512 + 2048);
    bf16x8 A1l = *(const bf16x8*)(ab + 512 + 4096);

#define MM(AH, AM, AL, BH, BM, BL, ACC)                                       \
    ACC = __builtin_amdgcn_mfma_f32_16x16x32_bf16(AH, BH, ACC, 0, 0, 0);      \
    ACC = __builtin_amdgcn_mfma_f32_16x16x32_bf16(AH, BM, ACC, 0, 0, 0);      \
    ACC = __builtin_amdgcn_mfma_f32_16x16x32_bf16(AM, BH, ACC, 0, 0, 0);      \
    ACC = __builtin_amdgcn_mfma_f32_16x16x32_bf16(AH, BL, ACC, 0, 0, 0);      \
    ACC = __builtin_amdgcn_mfma_f32_16x16x32_bf16(AM, BM, ACC, 0, 0, 0);      \
    ACC = __builtin_amdgcn_mfma_f32_16x16x32_bf16(AL, BH, ACC, 0, 0, 0)

    MM(A0h, A0m, A0l, B0h, B0m, B0l, acc[0][0]);
    MM(A0h, A0m, A0l, B1h, B1m, B1l, acc[0][1]);
    MM(A1h, A1m, A1l, B0h, B0m, B0l, acc[1][0]);
    MM(A1h, A1m, A1l, B1h, B1m, B1l, acc[1][1]);
#undef MM
    bp += 6144;
    __syncthreads();
  }
#undef CVT_WRITE

  // store: C/D layout col = lane&15, row = (lane>>4)*4 + r  [m89-verified]
  const int r0 = (lane >> 4) * 4;
  const int cc = lane & 15;
#pragma unroll
  for (int mt = 0; mt < 2; ++mt)
#pragma unroll
    for (int rr = 0; rr < 4; ++rr) {
      const int t = T0 + th * 32 + mt * 16 + r0 + rr;
      float* p = part + ((size_t)split * N_TOK + t) * 64 + eh * 32 + cc;
      p[0]  = acc[mt][0][rr];
      p[16] = acc[mt][1][rr];
    }
}

// ---------------------------------------------------------------------------
// Epilogue: 256 blocks x 64 threads (1 token/thread, one wave per block).
// ---------------------------------------------------------------------------
__global__ __launch_bounds__(64)
void epilogue(const float* __restrict__ part, int nsplit,
              float* __restrict__ out,
              double* __restrict__ blk_ps,     // [256][64]
              double* __restrict__ blk_z,      // [256]
              unsigned* __restrict__ freq) {
  const int lane = threadIdx.x;                // 0..63
  const int t    = blockIdx.x * 64 + lane;

  float l[64];
  {
    const float* p0 = part + (size_t)t * 64;
#pragma unroll
    for (int q = 0; q < 16; ++q) {
      float4 a = *(const float4*)(p0 + q * 4);
      l[q * 4 + 0] = a.x; l[q * 4 + 1] = a.y;
      l[q * 4 + 2] = a.z; l[q * 4 + 3] = a.w;
    }
  }
  for (int s = 1; s < nsplit; ++s) {
    const float* ps = part + ((size_t)s * N_TOK + t) * 64;
#pragma unroll
    for (int q = 0; q < 16; ++q) {
      float4 a = *(const float4*)(ps + q * 4);
      l[q * 4 + 0] += a.x; l[q * 4 + 1] += a.y;
      l[q * 4 + 2] += a.z; l[q * 4 + 3] += a.w;
    }
  }

  float m = l[0];
#pragma unroll
  for (int e = 1; e < 64; ++e) m = fmaxf(m, l[e]);

  float sum = 0.f;
#pragma unroll
  for (int e = 0; e < 64; ++e) sum += __expf(l[e] - m);
  const float lse = m + __logf(sum);
  const float inv = 1.0f / sum;

  // top-2 scan, strict > keeps lowest index on ties (lax.top_k semantics)
  float v0 = l[0], v1 = -3.402823466e38f;
  int i0 = 0, i1 = 0;
#pragma unroll
  for (int e = 1; e < 64; ++e) {
    float le = l[e];
    bool g0 = le > v0;
    bool g1 = le > v1;
    float nv1 = g0 ? v0 : (g1 ? le : v1);
    int   ni1 = g0 ? i0 : (g1 ? e  : i1);
    float nv0 = g0 ? le : v0;
    int   ni0 = g0 ? e  : i0;
    v0 = nv0; i0 = ni0; v1 = nv1; i1 = ni1;
  }

  float d  = __expf(v1 - v0);
  float g0 = 1.0f / (1.0f + d);
  float g1 = d * g0;

  out[t * 2 + 0] = (float)i0;
  out[t * 2 + 1] = (float)i1;
  out[2 * N_TOK + t * 2 + 0] = g0;
  out[2 * N_TOK + t * 2 + 1] = g1;

  // freq histogram: LDS within block, one u32 atomic per expert per block
  __shared__ unsigned hist[64];
  hist[lane] = 0u;
  __syncthreads();
  atomicAdd(&hist[i0], 1u);
  atomicAdd(&hist[i1], 1u);
  __syncthreads();
  if (hist[lane]) atomicAdd(&freq[lane], hist[lane]);

  // p_sum: per-expert wave butterfly; lane e ends holding block-sum for e
  float myps = 0.f;
#pragma unroll
  for (int e = 0; e < 64; ++e) {
    float v = __expf(l[e] - m) * inv;
    v += __shfl_xor(v, 32, 64);
    v += __shfl_xor(v, 16, 64);
    v += __shfl_xor(v, 8, 64);
    v += __shfl_xor(v, 4, 64);
    v += __shfl_xor(v, 2, 64);
    v += __shfl_xor(v, 1, 64);
    myps = (lane == e) ? v : myps;
  }
  blk_ps[(size_t)blockIdx.x * 64 + lane] = (double)myps;

  float z = lse * lse;
  z += __shfl_xor(z, 32, 64);
  z += __shfl_xor(z, 16, 64);
  z += __shfl_xor(z, 8, 64);
  z += __shfl_xor(z, 4, 64);
  z += __shfl_xor(z, 2, 64);
  z += __shfl_xor(z, 1, 64);
  if (lane == 0) blk_z[blockIdx.x] = (double)z;
}

// ---------------------------------------------------------------------------
// Finalize: sum per-block partials, switchloss + 0.1*z_loss (1 block, 64 thr)
// ---------------------------------------------------------------------------
__global__ void finalize(const double* __restrict__ blk_ps,
                         const double* __restrict__ blk_z,
                         const unsigned* __restrict__ freq,
                         float* __restrict__ out_loss) {
  const int lane = threadIdx.x;
  double p = 0.0;
  for (int b = 0; b < 256; ++b) p += blk_ps[(size_t)b * 64 + lane];
  double zt = 0.0;
#pragma unroll
  for (int b = 0; b < 4; ++b) zt += blk_z[lane * 4 + b];
#pragma unroll
  for (int off = 32; off >= 1; off >>= 1) zt += __shfl_xor(zt, off, 64);

  double f = (double)freq[lane];
  double pa = fabs(p);
  double fa = fabs(f);
#pragma unroll
  for (int off = 32; off >= 1; off >>= 1) {
    pa += __shfl_xor(pa, off, 64);
    fa += __shfl_xor(fa, off, 64);
  }
  pa = pa > 1e-12 ? pa : 1e-12;
  fa = fa > 1e-12 ? fa : 1e-12;

  double s = (p / pa) * (f / fa);
#pragma unroll
  for (int off = 32; off >= 1; off >>= 1) s += __shfl_xor(s, off, 64);

  if (lane == 0) {
    double switchloss = 64.0 * s;
    double z_loss = zt / (double)N_TOK;
    out_loss[0] = (float)(switchloss + 0.1 * z_loss);
  }
}

extern "C" void kernel_launch(void* const* d_in, const int* in_sizes, int n_in,
                              void* d_out, int out_size, void* d_ws, size_t ws_size,
                              hipStream_t stream) {
  const float* x = (const float*)d_in[0];
  const float* W = (const float*)d_in[1];
  float* out = (float*)d_out;

  const size_t partB = (size_t)N_TOK * 64 * 4;           // 4 MB per split
  float* part = (float*)d_ws;
  size_t off = (size_t)SPLIT * partB;                    // 16 MB
  double* blk_ps = (double*)((char*)d_ws + off);         // 128 KB
  double* blk_z  = blk_ps + 256 * 64;                    // 2 KB
  unsigned* freq = (unsigned*)(blk_z + 256);             // 256 B
  size_t woff = (off + 256 * 64 * 8 + 256 * 8 + 64 * 4 + 255) & ~(size_t)255;
  unsigned short* Wp = (unsigned short*)((char*)d_ws + woff);  // 768 KB

  hipMemsetAsync(freq, 0, 64 * sizeof(unsigned), stream);

  pack_w<<<64, 256, 0, stream>>>(W, Wp);
  router_gemm<<<NTILE * SPLIT, 256, 0, stream>>>(x, Wp, part);
  epilogue<<<N_TOK / 64, 64, 0, stream>>>(part, SPLIT, out, blk_ps, blk_z, freq);
  finalize<<<1, 64, 0, stream>>>(blk_ps, blk_z, freq, out + 4 * N_TOK);
}

// Round 8
// 62.768 us; speedup vs baseline: 31.6172x; 1.0002x over previous
//
#include <hip/hip_runtime.h>
#include <hip/hip_bf16.h>
#include <math.h>

#define N_TOK 16384
#define D_DIM 2048
#define E_EXP 64
#define SPLIT 4
#define KPER  (D_DIM / SPLIT)   /* 512 */
#define NCH   (KPER / 32)       /* 16 K-chunks per block */
#define NTILE (N_TOK / 64)      /* 256 token tiles */

typedef __attribute__((ext_vector_type(8))) short bf16x8;
typedef __attribute__((ext_vector_type(4))) float f32x4;
typedef __attribute__((ext_vector_type(4))) unsigned int u32x4;

// pack two masked fp32 bit-patterns' high halves into one u32 of 2 bf16
// dst = [lo.b2, lo.b3, hi.b2, hi.b3]  (v_perm_b32, sel byte 0-3 from s1)
#define PACK2(HI, LO) __builtin_amdgcn_perm((HI), (LO), 0x07060302u)

// ---------------------------------------------------------------------------
// pack_w: W fp32 [64][2048] -> exact 3-limb bf16 split, frag-ordered:
// Wp[chunk c][kgroup g][tau][e][8 bf16]  (tau 0/1/2 = hi/mid/lo limb)
// Split is EXACT (masking; subtractions exact), so x*w error comes only from
// dropped ml/lm/ll cross terms (<= ~2^-23 rel) -- below fp32 summation noise.
// ---------------------------------------------------------------------------
__global__ void pack_w(const float* __restrict__ W,
                       unsigned short* __restrict__ Wp) {
  const int T = blockIdx.x * 256 + threadIdx.x;   // 16384 = 64c * 4g * 64e
  const int e = T & 63, g = (T >> 6) & 3, c = T >> 8;
  const float* src = W + (size_t)e * D_DIM + c * 32 + g * 8;
  float4 v0 = *(const float4*)src;
  float4 v1 = *(const float4*)(src + 4);
  float vv[8] = {v0.x, v0.y, v0.z, v0.w, v1.x, v1.y, v1.z, v1.w};
  unsigned hu[8], mu[8], lu[8];
#pragma unroll
  for (int j = 0; j < 8; ++j) {
    unsigned u = __float_as_uint(vv[j]);
    unsigned a = u & 0xffff0000u;
    float r = vv[j] - __uint_as_float(a);
    unsigned b = __float_as_uint(r) & 0xffff0000u;
    float r2 = r - __uint_as_float(b);
    unsigned d = __float_as_uint(r2) & 0xffff0000u;
    hu[j] = a; mu[j] = b; lu[j] = d;
  }
  unsigned ph[4], pm[4], pl[4];
#pragma unroll
  for (int q = 0; q < 4; ++q) {     // ascending k pairs: lo in low 16
    ph[q] = PACK2(hu[2 * q + 1], hu[2 * q]);
    pm[q] = PACK2(mu[2 * q + 1], mu[2 * q]);
    pl[q] = PACK2(lu[2 * q + 1], lu[2 * q]);
  }
  const size_t base = (size_t)c * 6144 + g * 1536 + e * 8;  // ushort units
  *(u32x4*)(Wp + base)        = *(u32x4*)ph;   // tau 0
  *(u32x4*)(Wp + base + 512)  = *(u32x4*)pm;   // tau 1
  *(u32x4*)(Wp + base + 1024) = *(u32x4*)pl;   // tau 2
}

// ---------------------------------------------------------------------------
// GEMM via mfma_f32_16x16x32_bf16, 6-term limb products.
// grid = NTILE*SPLIT = 1024 blocks, 256 thr (4 waves). Block tile 64tok x
// 64exp; wave = (tok-half, exp-half) -> 2x2 16x16 MFMA tiles, 24 MFMA/chunk.
// x converted to 3 bf16 LDS planes per chunk (dbuf, 1 barrier/chunk);
// W limbs read as B-frags directly from L2 (packed).
// LDS kgroup slots XOR-swizzled with (row>>1)&3 [T2]: un-swizzled A-reads
// had lanes 0-15 at stride-64B (banks {0,16} alternating) = 8-way conflict
// (~2.94x, m136); swizzle spreads 16 rows over 8 bank-quads = 2-way = free.
// Same involution on CVT write (bijective per 1KB window, structural-only).
// ---------------------------------------------------------------------------
__global__ __launch_bounds__(256)
void router_gemm(const float* __restrict__ x,
                 const unsigned short* __restrict__ Wp,
                 float* __restrict__ part) {
  // LDS: [2 buf][3 tau][64 rows][4 kgroup slots][8] bf16 = 24 KB
  __shared__ __align__(16) unsigned short s_x[2 * 3 * 64 * 32];
  const int tid  = threadIdx.x;
  const int lane = tid & 63;
  const int w    = tid >> 6;
  const int th   = w >> 1;            // token half (0/1)
  const int eh   = w & 1;             // expert half (0/1)
  const int tile  = blockIdx.x & (NTILE - 1);
  const int split = blockIdx.x >> 8;
  const int T0 = tile * 64;
  const int k0 = split * KPER;

  // conversion: thread covers row crow, k-group ckg (8 floats/chunk)
  const int crow = tid >> 2;
  const int ckg  = tid & 3;
  const float* xg = x + (size_t)(T0 + crow) * D_DIM + k0 + ckg * 8;
  // swizzled slot: ckg ^ ((crow>>1)&3)
  const int wbase = crow * 32 + ((ckg ^ ((crow >> 1) & 3)) << 3);

  // A-frag read: row = th*32 + (lane&15), want kgroup g = lane>>4
  const int arow  = th * 32 + (lane & 15);
  const int abase = arow * 32 + ((((lane >> 4) ^ ((arow >> 1) & 3))) << 3);
  // B-frag lane offset: g*1536 + e*8 (ushort), e = eh*32 + nt*16 + (lane&15)
  const int bl = (lane >> 4) * 1536 + (eh * 32 + (lane & 15)) * 8;

  f32x4 acc[2][2];
#pragma unroll
  for (int i = 0; i < 2; ++i)
#pragma unroll
    for (int j = 0; j < 2; ++j) acc[i][j] = (f32x4)0.f;

#define CVT_WRITE(BUF, V0, V1)                                              \
  do {                                                                      \
    float vv[8] = {V0.x, V0.y, V0.z, V0.w, V1.x, V1.y, V1.z, V1.w};         \
    unsigned hu[8], mu[8], lu[8];                                           \
    _Pragma("unroll") for (int j = 0; j < 8; ++j) {                         \
      unsigned u = __float_as_uint(vv[j]);                                  \
      unsigned a = u & 0xffff0000u;                                         \
      float r = vv[j] - __uint_as_float(a);                                 \
      unsigned b = __float_as_uint(r) & 0xffff0000u;                        \
      float r2 = r - __uint_as_float(b);                                    \
      unsigned d = __float_as_uint(r2) & 0xffff0000u;                       \
      hu[j] = a; mu[j] = b; lu[j] = d;                                      \
    }                                                                       \
    unsigned ph[4], pm[4], pl[4];                                           \
    _Pragma("unroll") for (int q = 0; q < 4; ++q) {                         \
      ph[q] = PACK2(hu[2 * q + 1], hu[2 * q]);                              \
      pm[q] = PACK2(mu[2 * q + 1], mu[2 * q]);                              \
      pl[q] = PACK2(lu[2 * q + 1], lu[2 * q]);                              \
    }                                                                       \
    *(u32x4*)&s_x[(BUF) * 6144 + 0 * 2048 + wbase] = *(u32x4*)ph;           \
    *(u32x4*)&s_x[(BUF) * 6144 + 1 * 2048 + wbase] = *(u32x4*)pm;           \
    *(u32x4*)&s_x[(BUF) * 6144 + 2 * 2048 + wbase] = *(u32x4*)pl;           \
  } while (0)

  // prolog: chunk 0 -> buf 0; prefetch chunk 1 into regs
  float4 rx0 = *(const float4*)xg;
  float4 rx1 = *(const float4*)(xg + 4);
  CVT_WRITE(0, rx0, rx1);
  rx0 = *(const float4*)(xg + 32);
  rx1 = *(const float4*)(xg + 36);
  __syncthreads();

  const unsigned short* bp = Wp + (size_t)(split * NCH) * 6144 + bl;

#pragma unroll 1
  for (int c = 0; c < NCH; ++c) {
    const int buf = c & 1;
    if (c + 1 < NCH) CVT_WRITE(buf ^ 1, rx0, rx1);   // regs hold chunk c+1
    if (c + 2 < NCH) {                               // prefetch chunk c+2
      rx0 = *(const float4*)(xg + (c + 2) * 32);
      rx1 = *(const float4*)(xg + (c + 2) * 32 + 4);
    }
    // B-frags for chunk c (L2-resident packed W), imm-offset loads
    bf16x8 B0h = *(const bf16x8*)(bp);
    bf16x8 B0m = *(const bf16x8*)(bp + 512);
    bf16x8 B0l = *(const bf16x8*)(bp + 1024);
    bf16x8 B1h = *(const bf16x8*)(bp + 128);
    bf16x8 B1m = *(const bf16x8*)(bp + 128 + 512);
    bf16x8 B1l = *(const bf16x8*)(bp + 128 + 1024);
    // A-frags from LDS
    const unsigned short* ab = &s_x[buf * 6144 + abase];
    bf16x8 A0h = *(const bf16x8*)(ab);
    bf16x8 A0m = *(const bf16x8*)(ab + 2048);
    bf16x8 A0l = *(const bf16x8*)(ab + 4096);
    bf16x8 A1h = *(const bf16x8*)(ab + 512);
    bf16x8 A1m = *(const bf16x8*)(ab + 512 + 2048);
    bf16x8 A1l = *(const bf16x8*)(ab + 512 + 4096);

#define MM(AH, AM, AL, BH, BM, BL, ACC)                                       \
    ACC = __builtin_amdgcn_mfma_f32_16x16x32_bf16(AH, BH, ACC, 0, 0, 0);      \
    ACC = __builtin_amdgcn_mfma_f32_16x16x32_bf16(AH, BM, ACC, 0, 0, 0);      \
    ACC = __builtin_amdgcn_mfma_f32_16x16x32_bf16(AM, BH, ACC, 0, 0, 0);      \
    ACC = __builtin_amdgcn_mfma_f32_16x16x32_bf16(AH, BL, ACC, 0, 0, 0);      \
    ACC = __builtin_amdgcn_mfma_f32_16x16x32_bf16(AM, BM, ACC, 0, 0, 0);      \
    ACC = __builtin_amdgcn_mfma_f32_16x16x32_bf16(AL, BH, ACC, 0, 0, 0)

    MM(A0h, A0m, A0l, B0h, B0m, B0l, acc[0][0]);
    MM(A0h, A0m, A0l, B1h, B1m, B1l, acc[0][1]);
    MM(A1h, A1m, A1l, B0h, B0m, B0l, acc[1][0]);
    MM(A1h, A1m, A1l, B1h, B1m, B1l, acc[1][1]);
#undef MM
    bp += 6144;
    __syncthreads();
  }
#undef CVT_WRITE

  // store: C/D layout col = lane&15, row = (lane>>4)*4 + r  [m89-verified]
  const int r0 = (lane >> 4) * 4;
  const int cc = lane & 15;
#pragma unroll
  for (int mt = 0; mt < 2; ++mt)
#pragma unroll
    for (int rr = 0; rr < 4; ++rr) {
      const int t = T0 + th * 32 + mt * 16 + r0 + rr;
      float* p = part + ((size_t)split * N_TOK + t) * 64 + eh * 32 + cc;
      p[0]  = acc[mt][0][rr];
      p[16] = acc[mt][1][rr];
    }
}

// ---------------------------------------------------------------------------
// Epilogue: 256 blocks x 64 threads (1 token/thread, one wave per block).
// ---------------------------------------------------------------------------
__global__ __launch_bounds__(64)
void epilogue(const float* __restrict__ part, int nsplit,
              float* __restrict__ out,
              double* __restrict__ blk_ps,     // [256][64]
              double* __restrict__ blk_z,      // [256]
              unsigned* __restrict__ freq) {
  const int lane = threadIdx.x;                // 0..63
  const int t    = blockIdx.x * 64 + lane;

  float l[64];
  {
    const float* p0 = part + (size_t)t * 64;
#pragma unroll
    for (int q = 0; q < 16; ++q) {
      float4 a = *(const float4*)(p0 + q * 4);
      l[q * 4 + 0] = a.x; l[q * 4 + 1] = a.y;
      l[q * 4 + 2] = a.z; l[q * 4 + 3] = a.w;
    }
  }
  for (int s = 1; s < nsplit; ++s) {
    const float* ps = part + ((size_t)s * N_TOK + t) * 64;
#pragma unroll
    for (int q = 0; q < 16; ++q) {
      float4 a = *(const float4*)(ps + q * 4);
      l[q * 4 + 0] += a.x; l[q * 4 + 1] += a.y;
      l[q * 4 + 2] += a.z; l[q * 4 + 3] += a.w;
    }
  }

  float m = l[0];
#pragma unroll
  for (int e = 1; e < 64; ++e) m = fmaxf(m, l[e]);

  float sum = 0.f;
#pragma unroll
  for (int e = 0; e < 64; ++e) sum += __expf(l[e] - m);
  const float lse = m + __logf(sum);
  const float inv = 1.0f / sum;

  // top-2 scan, strict > keeps lowest index on ties (lax.top_k semantics)
  float v0 = l[0], v1 = -3.402823466e38f;
  int i0 = 0, i1 = 0;
#pragma unroll
  for (int e = 1; e < 64; ++e) {
    float le = l[e];
    bool g0 = le > v0;
    bool g1 = le > v1;
    float nv1 = g0 ? v0 : (g1 ? le : v1);
    int   ni1 = g0 ? i0 : (g1 ? e  : i1);
    float nv0 = g0 ? le : v0;
    int   ni0 = g0 ? e  : i0;
    v0 = nv0; i0 = ni0; v1 = nv1; i1 = ni1;
  }

  float d  = __expf(v1 - v0);
  float g0 = 1.0f / (1.0f + d);
  float g1 = d * g0;

  out[t * 2 + 0] = (float)i0;
  out[t * 2 + 1] = (float)i1;
  out[2 * N_TOK + t * 2 + 0] = g0;
  out[2 * N_TOK + t * 2 + 1] = g1;

  // freq histogram: LDS within block, one u32 atomic per expert per block
  __shared__ unsigned hist[64];
  hist[lane] = 0u;
  __syncthreads();
  atomicAdd(&hist[i0], 1u);
  atomicAdd(&hist[i1], 1u);
  __syncthreads();
  if (hist[lane]) atomicAdd(&freq[lane], hist[lane]);

  // p_sum: per-expert wave butterfly; lane e ends holding block-sum for e
  float myps = 0.f;
#pragma unroll
  for (int e = 0; e < 64; ++e) {
    float v = __expf(l[e] - m) * inv;
    v += __shfl_xor(v, 32, 64);
    v += __shfl_xor(v, 16, 64);
    v += __shfl_xor(v, 8, 64);
    v += __shfl_xor(v, 4, 64);
    v += __shfl_xor(v, 2, 64);
    v += __shfl_xor(v, 1, 64);
    myps = (lane == e) ? v : myps;
  }
  blk_ps[(size_t)blockIdx.x * 64 + lane] = (double)myps;

  float z = lse * lse;
  z += __shfl_xor(z, 32, 64);
  z += __shfl_xor(z, 16, 64);
  z += __shfl_xor(z, 8, 64);
  z += __shfl_xor(z, 4, 64);
  z += __shfl_xor(z, 2, 64);
  z += __shfl_xor(z, 1, 64);
  if (lane == 0) blk_z[blockIdx.x] = (double)z;
}

// ---------------------------------------------------------------------------
// Finalize: sum per-block partials, switchloss + 0.1*z_loss (1 block, 64 thr)
// ---------------------------------------------------------------------------
__global__ void finalize(const double* __restrict__ blk_ps,
                         const double* __restrict__ blk_z,
                         const unsigned* __restrict__ freq,
                         float* __restrict__ out_loss) {
  const int lane = threadIdx.x;
  double p = 0.0;
  for (int b = 0; b < 256; ++b) p += blk_ps[(size_t)b * 64 + lane];
  double zt = 0.0;
#pragma unroll
  for (int b = 0; b < 4; ++b) zt += blk_z[lane * 4 + b];
#pragma unroll
  for (int off = 32; off >= 1; off >>= 1) zt += __shfl_xor(zt, off, 64);

  double f = (double)freq[lane];
  double pa = fabs(p);
  double fa = fabs(f);
#pragma unroll
  for (int off = 32; off >= 1; off >>= 1) {
    pa += __shfl_xor(pa, off, 64);
    fa += __shfl_xor(fa, off, 64);
  }
  pa = pa > 1e-12 ? pa : 1e-12;
  fa = fa > 1e-12 ? fa : 1e-12;

  double s = (p / pa) * (f / fa);
#pragma unroll
  for (int off = 32; off >= 1; off >>= 1) s += __shfl_xor(s, off, 64);

  if (lane == 0) {
    double switchloss = 64.0 * s;
    double z_loss = zt / (double)N_TOK;
    out_loss[0] = (float)(switchloss + 0.1 * z_loss);
  }
}

extern "C" void kernel_launch(void* const* d_in, const int* in_sizes, int n_in,
                              void* d_out, int out_size, void* d_ws, size_t ws_size,
                              hipStream_t stream) {
  const float* x = (const float*)d_in[0];
  const float* W = (const float*)d_in[1];
  float* out = (float*)d_out;

  const size_t partB = (size_t)N_TOK * 64 * 4;           // 4 MB per split
  float* part = (float*)d_ws;
  size_t off = (size_t)SPLIT * partB;                    // 16 MB
  double* blk_ps = (double*)((char*)d_ws + off);         // 128 KB
  double* blk_z  = blk_ps + 256 * 64;                    // 2 KB
  unsigned* freq = (unsigned*)(blk_z + 256);             // 256 B
  size_t woff = (off + 256 * 64 * 8 + 256 * 8 + 64 * 4 + 255) & ~(size_t)255;
  unsigned short* Wp = (unsigned short*)((char*)d_ws + woff);  // 768 KB

  hipMemsetAsync(freq, 0, 64 * sizeof(unsigned), stream);

  pack_w<<<64, 256, 0, stream>>>(W, Wp);
  router_gemm<<<NTILE * SPLIT, 256, 0, stream>>>(x, Wp, part);
  epilogue<<<N_TOK / 64, 64, 0, stream>>>(part, SPLIT, out, blk_ps, blk_z, freq);
  finalize<<<1, 64, 0, stream>>>(blk_ps, blk_z, freq, out + 4 * N_TOK);
}